// Round 6
// baseline (348.959 us; speedup 1.0000x reference)
//
#include <hip/hip_runtime.h>
#include <hip/hip_bf16.h>

#define DD 128

typedef short bf16x8 __attribute__((ext_vector_type(8)));
typedef float f32x4 __attribute__((ext_vector_type(4)));

__device__ __forceinline__ float bf2f_lo(unsigned int u) {
    union { unsigned int v; float f; } x; x.v = u << 16; return x.f;
}
__device__ __forceinline__ float bf2f_hi(unsigned int u) {
    union { unsigned int v; float f; } x; x.v = u & 0xFFFF0000u; return x.f;
}
__device__ __forceinline__ unsigned short f2bf(float f) {
    union { float f; unsigned int u; } x; x.f = f;
    unsigned int u = x.u;
    unsigned int r = (u + 0x7FFFu + ((u >> 16) & 1u)) >> 16;  // RNE
    return (unsigned short)r;
}

// ---- MFMA GEMM: C[M x NOUT] = act( A[M x K] @ W[NOUT x K]^T + bias ) ----
// MODE 0: PReLU on A during staging; epilogue: Hb = bf16(acc) only
// MODE 1: bias + ReLU -> Hb (bf16)
// MODE 2: bias -> Cf (f32)
template<int K, int NOUT, int MODE, bool ABF>
__global__ __launch_bounds__(256) void mgemm_k(
    const void* __restrict__ Ap, const float* __restrict__ W,
    const float* __restrict__ bias, float* __restrict__ Cf,
    unsigned short* __restrict__ Hb,
    const float* __restrict__ prelu_a, int M)
{
    const int BM = 64, BN = 128, BK = 32;
    __shared__ unsigned short Asl[BM][BK + 8];
    __shared__ unsigned short Bsl[BN][BK + 8];
    const int bm = blockIdx.x * BM;
    const int bn = blockIdx.y * BN;
    const int tid = threadIdx.x;
    const int wid = tid >> 6, lane = tid & 63;
    const int wm = wid >> 1, wn = wid & 1;
    float pa = (MODE == 0) ? prelu_a[0] : 0.f;

    f32x4 acc[2][4];
    const f32x4 zz = {0.f, 0.f, 0.f, 0.f};
    #pragma unroll
    for (int i = 0; i < 2; ++i)
        #pragma unroll
        for (int j = 0; j < 4; ++j) acc[i][j] = zz;

    for (int k0 = 0; k0 < K; k0 += BK) {
        #pragma unroll
        for (int idx = tid; idx < BM * 8; idx += 256) {
            int r = idx >> 3, kq = idx & 7;
            int gr = bm + r; if (gr > M - 1) gr = M - 1;
            ushort4 w;
            if (ABF) {
                w = *(const ushort4*)((const unsigned short*)Ap + (size_t)gr * K + k0 + kq * 4);
            } else {
                float4 v = *(const float4*)((const float*)Ap + (size_t)gr * K + k0 + kq * 4);
                if (MODE == 0) {
                    v.x = v.x >= 0.f ? v.x : pa * v.x;
                    v.y = v.y >= 0.f ? v.y : pa * v.y;
                    v.z = v.z >= 0.f ? v.z : pa * v.z;
                    v.w = v.w >= 0.f ? v.w : pa * v.w;
                }
                w.x = f2bf(v.x); w.y = f2bf(v.y); w.z = f2bf(v.z); w.w = f2bf(v.w);
            }
            *(ushort4*)&Asl[r][kq * 4] = w;
        }
        #pragma unroll
        for (int idx = tid; idx < BN * 8; idx += 256) {
            int r = idx >> 3, kq = idx & 7;
            float4 v = *(const float4*)&W[(size_t)(bn + r) * K + k0 + kq * 4];
            ushort4 w;
            w.x = f2bf(v.x); w.y = f2bf(v.y); w.z = f2bf(v.z); w.w = f2bf(v.w);
            *(ushort4*)&Bsl[r][kq * 4] = w;
        }
        __syncthreads();

        const int k8 = (lane >> 4) * 8;
        bf16x8 af[2], bfr[4];
        #pragma unroll
        for (int i = 0; i < 2; ++i)
            af[i] = *(const bf16x8*)&Asl[wm * 32 + i * 16 + (lane & 15)][k8];
        #pragma unroll
        for (int j = 0; j < 4; ++j)
            bfr[j] = *(const bf16x8*)&Bsl[wn * 64 + j * 16 + (lane & 15)][k8];
        #pragma unroll
        for (int i = 0; i < 2; ++i)
            #pragma unroll
            for (int j = 0; j < 4; ++j)
                acc[i][j] = __builtin_amdgcn_mfma_f32_16x16x32_bf16(af[i], bfr[j], acc[i][j], 0, 0, 0);
        __syncthreads();
    }

    const int rq = (lane >> 4) * 4;
    const int cb = lane & 15;
    #pragma unroll
    for (int i = 0; i < 2; ++i) {
        #pragma unroll
        for (int j = 0; j < 4; ++j) {
            int c = bn + wn * 64 + j * 16 + cb;
            float bi = 0.f;
            if (MODE == 1 || MODE == 2) bi = bias[c];
            int r0 = bm + wm * 32 + i * 16 + rq;
            #pragma unroll
            for (int t = 0; t < 4; ++t) {
                int r = r0 + t;
                if (r >= M) continue;
                float v = acc[i][j][t];
                if (MODE == 0) {
                    Hb[(size_t)r * NOUT + c] = f2bf(v);
                } else if (MODE == 1) {
                    v = fmaxf(v + bi, 0.f);
                    Hb[(size_t)r * NOUT + c] = f2bf(v);
                } else {
                    Cf[(size_t)r * NOUT + c] = v + bi;
                }
            }
        }
    }
}

// ---- cache-local CSR build ----
// record: src(17) | combo<<17 (4) | dstlocal<<21 (9)

#define SBSH 9           // superbucket = 512 dst nodes
#define SBN  512
#define NBP 256

__global__ __launch_bounds__(256) void sbhist_k(const int* __restrict__ ei,
                                                int* __restrict__ bh,
                                                int E, int chunk, int nsb) {
    __shared__ int h4[4][256];
    int wid = threadIdx.x >> 6;
    for (int i = threadIdx.x; i < 4 * 256; i += 256) ((int*)h4)[i] = 0;
    __syncthreads();
    int b = blockIdx.x;
    int beg = b * chunk, end = min(E, beg + chunk);
    for (int e = beg + threadIdx.x; e < end; e += 256)
        atomicAdd(&h4[wid][ei[E + e] >> SBSH], 1);
    __syncthreads();
    for (int i = threadIdx.x; i < nsb; i += 256)
        bh[i * NBP + b] = h4[0][i] + h4[1][i] + h4[2][i] + h4[3][i];
}

__global__ __launch_bounds__(256) void sbscan_k(const int* __restrict__ bh,
                                                int* __restrict__ bho,
                                                int ntot, int* __restrict__ offs,
                                                int M, int E) {
    __shared__ int ws[4];
    int ch = (ntot + 255) / 256;
    int beg = threadIdx.x * ch, end = min(ntot, beg + ch);
    int s = 0;
    for (int i = beg; i < end; ++i) s += bh[i];
    int lane = threadIdx.x & 63, wid = threadIdx.x >> 6;
    int ss = s;
    #pragma unroll
    for (int o = 1; o < 64; o <<= 1) { int t = __shfl_up(ss, o, 64); if (lane >= o) ss += t; }
    if (lane == 63) ws[wid] = ss;
    __syncthreads();
    if (threadIdx.x == 0) { int c = 0; for (int w = 0; w < 4; ++w) { int t = ws[w]; ws[w] = c; c += t; } }
    __syncthreads();
    int excl = ss - s + ws[wid];
    for (int i = beg; i < end; ++i) { int t = bh[i]; bho[i] = excl; excl += t; }
    if (threadIdx.x == 0) offs[M] = E;
}

__global__ __launch_bounds__(256) void part_k(const int* __restrict__ ei,
                                              const int* __restrict__ ea,
                                              const int* __restrict__ bho,
                                              int* __restrict__ rec,
                                              int E, int chunk, int nsb) {
    __shared__ int cur[256];
    int b = blockIdx.x;
    for (int i = threadIdx.x; i < nsb; i += 256) cur[i] = bho[i * NBP + b];
    __syncthreads();
    int beg = b * chunk, end = min(E, beg + chunk);
    for (int e = beg + threadIdx.x; e < end; e += 256) {
        int src = ei[e];
        int dst = ei[E + e];
        int a0 = ea[2 * e], a1 = ea[2 * e + 1];
        int pos = atomicAdd(&cur[dst >> SBSH], 1);
        rec[pos] = src | ((a0 * 3 + a1) << 17) | ((dst & (SBN - 1)) << 21);
    }
}

__global__ __launch_bounds__(1024) void csr_k(const int* __restrict__ rec,
                                              const int* __restrict__ bho,
                                              int* __restrict__ offs,
                                              int* __restrict__ packed,
                                              int nsb, int M, int E) {
    __shared__ int hist[SBN];
    __shared__ int lstart[SBN];
    __shared__ int wsum[16];
    int s = blockIdx.x;
    int t = threadIdx.x;
    int sb0 = bho[s * NBP];
    int sb1 = (s == nsb - 1) ? E : bho[(s + 1) * NBP];
    if (t < SBN) hist[t] = 0;
    __syncthreads();
    for (int i = sb0 + t; i < sb1; i += 1024)
        atomicAdd(&hist[(rec[i] >> 21) & (SBN - 1)], 1);
    __syncthreads();
    int v = (t < SBN) ? hist[t] : 0;
    int lane = t & 63, wid = t >> 6;
    int ss = v;
    #pragma unroll
    for (int o = 1; o < 64; o <<= 1) { int u = __shfl_up(ss, o, 64); if (lane >= o) ss += u; }
    if (lane == 63) wsum[wid] = ss;
    __syncthreads();
    if (t == 0) { int c = 0; for (int w = 0; w < 16; ++w) { int x = wsum[w]; wsum[w] = c; c += x; } }
    __syncthreads();
    int excl = ss - v + wsum[wid];
    if (t < SBN) {
        lstart[t] = excl;
        int node = (s << SBSH) + t;
        if (node < M) offs[node] = sb0 + excl;
        hist[t] = 0;
    }
    __syncthreads();
    for (int i = sb0 + t; i < sb1; i += 1024) {
        int r = rec[i];
        int dl = (r >> 21) & (SBN - 1);
        int pos = sb0 + lstart[dl] + atomicAdd(&hist[dl], 1);
        packed[pos] = r & 0x1FFFFF;
    }
}

__device__ __forceinline__ void edge_reduce(const unsigned short* __restrict__ h,
                                            const int* __restrict__ packed,
                                            const float (*emb12)[DD],
                                            int c2, int s, int t, float2& acc) {
    int e = s;
    for (; e + 8 <= t; e += 8) {
        int p[8]; unsigned int hv[8]; float2 m[8];
        #pragma unroll
        for (int i = 0; i < 8; ++i) p[i] = packed[e + i];
        #pragma unroll
        for (int i = 0; i < 8; ++i)
            hv[i] = *(const unsigned int*)&h[(size_t)(p[i] & 0x1FFFF) * DD + c2];
        #pragma unroll
        for (int i = 0; i < 8; ++i)
            m[i] = *(const float2*)&emb12[(p[i] >> 17) & 15][c2];
        #pragma unroll
        for (int i = 0; i < 8; ++i) {
            acc.x += bf2f_lo(hv[i]) + m[i].x;
            acc.y += bf2f_hi(hv[i]) + m[i].y;
        }
    }
    if (e + 4 <= t) {
        int p[4]; unsigned int hv[4]; float2 m[4];
        #pragma unroll
        for (int i = 0; i < 4; ++i) p[i] = packed[e + i];
        #pragma unroll
        for (int i = 0; i < 4; ++i)
            hv[i] = *(const unsigned int*)&h[(size_t)(p[i] & 0x1FFFF) * DD + c2];
        #pragma unroll
        for (int i = 0; i < 4; ++i)
            m[i] = *(const float2*)&emb12[(p[i] >> 17) & 15][c2];
        #pragma unroll
        for (int i = 0; i < 4; ++i) {
            acc.x += bf2f_lo(hv[i]) + m[i].x;
            acc.y += bf2f_hi(hv[i]) + m[i].y;
        }
        e += 4;
    }
    for (; e < t; ++e) {
        int p = packed[e];
        unsigned int hv = *(const unsigned int*)&h[(size_t)(p & 0x1FFFF) * DD + c2];
        float2 m = *(const float2*)&emb12[(p >> 17) & 15][c2];
        acc.x += bf2f_lo(hv) + m.x;
        acc.y += bf2f_hi(hv) + m.y;
    }
}

// per-dst gather-reduce: 2 waves per row (edge-split), LDS combine
__global__ __launch_bounds__(256) void agg_k(const unsigned short* __restrict__ h,
                                             const int* __restrict__ packed,
                                             const int* __restrict__ offs,
                                             const float* __restrict__ emb1,
                                             const float* __restrict__ emb2,
                                             unsigned int* __restrict__ aggb, int M) {
    __shared__ float emb12[10][DD];
    __shared__ float prt[2][DD];
    for (int t = threadIdx.x; t < 10 * DD; t += 256) {
        int c = t >> 7, col = t & 127;
        float v;
        if (c == 9) v = emb1[4 * DD + col] + emb2[col];          // self-loop emb
        else        v = emb1[(c / 3) * DD + col] + emb2[(c % 3) * DD + col];
        emb12[c][col] = v;
    }
    __syncthreads();
    int wid = threadIdx.x >> 6, lane = threadIdx.x & 63;
    int row = wid >> 1;          // 0..1
    int half = wid & 1;
    int n = blockIdx.x * 2 + row;
    bool active = n < M;
    int c2 = lane * 2;
    float2 acc = {0.f, 0.f};
    if (active) {
        n = __builtin_amdgcn_readfirstlane(n);
        int beg = offs[n], end = offs[n + 1];
        int mid = (beg + end + 1) >> 1;
        int s = half ? mid : beg;
        int t = half ? end : mid;
        if (!half) {
            unsigned int hn = *(const unsigned int*)&h[(size_t)n * DD + c2];
            float2 se = *(const float2*)&emb12[9][c2];
            acc.x = bf2f_lo(hn) + se.x;
            acc.y = bf2f_hi(hn) + se.y;
        }
        edge_reduce(h, packed, emb12, c2, s, t, acc);
    }
    if (half) { prt[row][c2] = acc.x; prt[row][c2 + 1] = acc.y; }
    __syncthreads();
    if (active && !half) {
        acc.x += prt[row][c2];
        acc.y += prt[row][c2 + 1];
        aggb[((size_t)n * DD + c2) >> 1] = ((unsigned int)f2bf(acc.y) << 16) | f2bf(acc.x);
    }
}

extern "C" void kernel_launch(void* const* d_in, const int* in_sizes, int n_in,
                              void* d_out, int out_size, void* d_ws, size_t ws_size,
                              hipStream_t stream) {
    const float* x     = (const float*)d_in[0];
    const int*   ei    = (const int*)d_in[1];
    const int*   ea    = (const int*)d_in[2];
    const float* pa    = (const float*)d_in[3];
    const float* Wenc  = (const float*)d_in[4];
    const float* emb1  = (const float*)d_in[5];
    const float* emb2  = (const float*)d_in[6];
    const float* W1    = (const float*)d_in[7];
    const float* b1    = (const float*)d_in[8];
    const float* W2    = (const float*)d_in[9];
    const float* b2    = (const float*)d_in[10];
    float* out = (float*)d_out;

    const int M = in_sizes[0] / DD;
    const int E = in_sizes[1] / 2;
    const int nsb = (M + SBN - 1) >> SBSH;
    const int chunk = (E + NBP - 1) / NBP;

    char* ws = (char*)d_ws;
    size_t o = 0;
    unsigned short* h_bf  = (unsigned short*)(ws + o); o += (size_t)M * DD * 2;
    unsigned int*   aggb  = (unsigned int*)(ws + o);   o += (size_t)M * DD * 2;
    // overlay: CSR scratch (dead after agg_k) aliased with hid (written by GEMM2)
    char* reg = ws + o;
    unsigned short* hid = (unsigned short*)reg;                 // M*256 bf16
    int* rec    = (int*)reg;
    int* packed = (int*)(reg + (size_t)E * 4);
    int* offs   = (int*)(reg + (size_t)E * 8);
    int* bh     = (int*)(reg + (size_t)E * 8 + (size_t)(M + 1) * 4);
    int* bho    = bh + 256 * NBP;

    const int gm = (M + 63) / 64;
    dim3 blk(256);

    sbhist_k<<<dim3(NBP), blk, 0, stream>>>(ei, bh, E, chunk, nsb);
    sbscan_k<<<dim3(1), blk, 0, stream>>>(bh, bho, nsb * NBP, offs, M, E);
    part_k<<<dim3(NBP), blk, 0, stream>>>(ei, ea, bho, rec, E, chunk, nsb);
    csr_k<<<dim3(nsb), dim3(1024), 0, stream>>>(rec, bho, offs, packed, nsb, M, E);

    // h_bf = bf16( PReLU(x) @ Wenc^T )
    mgemm_k<128, 128, 0, false><<<dim3(gm, 1), blk, 0, stream>>>(
        x, Wenc, nullptr, nullptr, h_bf, pa, M);

    agg_k<<<dim3((M + 1) / 2), blk, 0, stream>>>(h_bf, packed, offs, emb1, emb2, aggb, M);

    // hid = bf16(relu(aggb @ W1^T + b1))
    mgemm_k<128, 256, 1, true><<<dim3(gm, 2), blk, 0, stream>>>(
        aggb, W1, b1, nullptr, hid, nullptr, M);

    // out = hid @ W2^T + b2
    mgemm_k<256, 128, 2, true><<<dim3(gm, 1), blk, 0, stream>>>(
        hid, W2, b2, out, nullptr, nullptr, M);
}

// Round 7
// 259.490 us; speedup vs baseline: 1.3448x; 1.3448x over previous
//
#include <hip/hip_runtime.h>
#include <hip/hip_bf16.h>

#define DD 128

typedef short bf16x8 __attribute__((ext_vector_type(8)));
typedef float f32x4 __attribute__((ext_vector_type(4)));

__device__ __forceinline__ float bf2f_lo(unsigned int u) {
    union { unsigned int v; float f; } x; x.v = u << 16; return x.f;
}
__device__ __forceinline__ float bf2f_hi(unsigned int u) {
    union { unsigned int v; float f; } x; x.v = u & 0xFFFF0000u; return x.f;
}
__device__ __forceinline__ unsigned short f2bf(float f) {
    union { float f; unsigned int u; } x; x.f = f;
    unsigned int u = x.u;
    unsigned int r = (u + 0x7FFFu + ((u >> 16) & 1u)) >> 16;  // RNE
    return (unsigned short)r;
}

// ---- MFMA GEMM v2: W staged in LDS once; A streamed global->frags ----
// C[M x NOUT] = act( A[M x K] @ W[NOUT x K]^T + bias ), 128 cols per block
// MODE 0: PReLU on A during frag load; Hb = bf16(acc)
// MODE 1: bias + ReLU -> Hb (bf16)
// MODE 2: bias -> Cf (f32)
template<int K, int NOUT, int MODE, bool ABF>
__global__ __launch_bounds__(256) void gemm2_k(
    const void* __restrict__ Ap, const float* __restrict__ W,
    const float* __restrict__ bias, float* __restrict__ Cf,
    unsigned short* __restrict__ Hb,
    const float* __restrict__ prelu_a, int M)
{
    const int KF = K / 32;                  // k-frags per row
    __shared__ unsigned short Wl[128][K + 8];   // stride 272/528B -> 2-way banks (free)
    const int bn = blockIdx.y * 128;
    const int tid = threadIdx.x;
    const int wid = tid >> 6, lane = tid & 63;
    const float pa = (MODE == 0) ? prelu_a[0] : 0.f;

    // stage W panel: 128 rows x K (f32 -> bf16), once
    #pragma unroll
    for (int idx = tid; idx < 128 * K / 4; idx += 256) {
        int n = idx / (K / 4), kq = idx % (K / 4);
        float4 v = *(const float4*)&W[(size_t)(bn + n) * K + kq * 4];
        ushort4 w;
        w.x = f2bf(v.x); w.y = f2bf(v.y); w.z = f2bf(v.z); w.w = f2bf(v.w);
        *(ushort4*)&Wl[n][kq * 4] = w;
    }
    __syncthreads();

    // each wave: 32 rows (2 row-frags), streamed from global
    const int r0 = blockIdx.x * 128 + wid * 32;
    const int rl = lane & 15, kb = (lane >> 4) * 8;

    bf16x8 af[2][KF];
    #pragma unroll
    for (int rf = 0; rf < 2; ++rf) {
        int row = r0 + rf * 16 + rl; if (row > M - 1) row = M - 1;
        #pragma unroll
        for (int kf = 0; kf < KF; ++kf) {
            if (ABF) {
                af[rf][kf] = *(const bf16x8*)((const unsigned short*)Ap + (size_t)row * K + kf * 32 + kb);
            } else {
                const float* Af = (const float*)Ap;
                float4 v0 = *(const float4*)&Af[(size_t)row * K + kf * 32 + kb];
                float4 v1 = *(const float4*)&Af[(size_t)row * K + kf * 32 + kb + 4];
                if (MODE == 0) {
                    v0.x = v0.x >= 0.f ? v0.x : pa * v0.x;
                    v0.y = v0.y >= 0.f ? v0.y : pa * v0.y;
                    v0.z = v0.z >= 0.f ? v0.z : pa * v0.z;
                    v0.w = v0.w >= 0.f ? v0.w : pa * v0.w;
                    v1.x = v1.x >= 0.f ? v1.x : pa * v1.x;
                    v1.y = v1.y >= 0.f ? v1.y : pa * v1.y;
                    v1.z = v1.z >= 0.f ? v1.z : pa * v1.z;
                    v1.w = v1.w >= 0.f ? v1.w : pa * v1.w;
                }
                bf16x8 t;
                t[0] = (short)f2bf(v0.x); t[1] = (short)f2bf(v0.y);
                t[2] = (short)f2bf(v0.z); t[3] = (short)f2bf(v0.w);
                t[4] = (short)f2bf(v1.x); t[5] = (short)f2bf(v1.y);
                t[6] = (short)f2bf(v1.z); t[7] = (short)f2bf(v1.w);
                af[rf][kf] = t;
            }
        }
    }

    f32x4 acc[8][2];
    const f32x4 zz = {0.f, 0.f, 0.f, 0.f};
    #pragma unroll
    for (int nt = 0; nt < 8; ++nt) { acc[nt][0] = zz; acc[nt][1] = zz; }

    #pragma unroll
    for (int nt = 0; nt < 8; ++nt) {
        bf16x8 bf[KF];
        #pragma unroll
        for (int kf = 0; kf < KF; ++kf)
            bf[kf] = *(const bf16x8*)&Wl[nt * 16 + rl][kf * 32 + kb];
        #pragma unroll
        for (int rf = 0; rf < 2; ++rf)
            #pragma unroll
            for (int kf = 0; kf < KF; ++kf)
                acc[nt][rf] = __builtin_amdgcn_mfma_f32_16x16x32_bf16(af[rf][kf], bf[kf], acc[nt][rf], 0, 0, 0);
    }

    const int rq = (lane >> 4) * 4;
    #pragma unroll
    for (int nt = 0; nt < 8; ++nt) {
        int c = bn + nt * 16 + rl;
        float bi = 0.f;
        if (MODE == 1 || MODE == 2) bi = bias[c];
        #pragma unroll
        for (int rf = 0; rf < 2; ++rf) {
            int rb = r0 + rf * 16 + rq;
            #pragma unroll
            for (int t = 0; t < 4; ++t) {
                int r = rb + t;
                if (r >= M) continue;
                float v = acc[nt][rf][t];
                if (MODE == 0) {
                    Hb[(size_t)r * NOUT + c] = f2bf(v);
                } else if (MODE == 1) {
                    v = fmaxf(v + bi, 0.f);
                    Hb[(size_t)r * NOUT + c] = f2bf(v);
                } else {
                    Cf[(size_t)r * NOUT + c] = v + bi;
                }
            }
        }
    }
}

// ---- cache-local CSR build ----
// record: src(17) | combo<<17 (4) | dstlocal<<21 (10)

#define SBSH 10          // superbucket = 1024 dst nodes
#define SBN  1024
#define NBP 256

__global__ __launch_bounds__(256) void sbhist_k(const int* __restrict__ ei,
                                                int* __restrict__ bh,
                                                int E, int chunk, int nsb) {
    __shared__ int h4[4][128];
    int wid = threadIdx.x >> 6;
    for (int i = threadIdx.x; i < 4 * 128; i += 256) ((int*)h4)[i] = 0;
    __syncthreads();
    int b = blockIdx.x;
    int beg = b * chunk, end = min(E, beg + chunk);
    for (int e = beg + threadIdx.x; e < end; e += 256)
        atomicAdd(&h4[wid][ei[E + e] >> SBSH], 1);
    __syncthreads();
    for (int i = threadIdx.x; i < nsb; i += 256)
        bh[i * NBP + b] = h4[0][i] + h4[1][i] + h4[2][i] + h4[3][i];
}

__global__ __launch_bounds__(256) void sbscan_k(const int* __restrict__ bh,
                                                int* __restrict__ bho,
                                                int ntot, int* __restrict__ offs,
                                                int M, int E) {
    __shared__ int ws[4];
    int ch = (ntot + 255) / 256;
    int beg = threadIdx.x * ch, end = min(ntot, beg + ch);
    int s = 0;
    for (int i = beg; i < end; ++i) s += bh[i];
    int lane = threadIdx.x & 63, wid = threadIdx.x >> 6;
    int ss = s;
    #pragma unroll
    for (int o = 1; o < 64; o <<= 1) { int t = __shfl_up(ss, o, 64); if (lane >= o) ss += t; }
    if (lane == 63) ws[wid] = ss;
    __syncthreads();
    if (threadIdx.x == 0) { int c = 0; for (int w = 0; w < 4; ++w) { int t = ws[w]; ws[w] = c; c += t; } }
    __syncthreads();
    int excl = ss - s + ws[wid];
    for (int i = beg; i < end; ++i) { int t = bh[i]; bho[i] = excl; excl += t; }
    if (threadIdx.x == 0) offs[M] = E;
}

__global__ __launch_bounds__(256) void part_k(const int* __restrict__ ei,
                                              const int* __restrict__ ea,
                                              const int* __restrict__ bho,
                                              int* __restrict__ rec,
                                              int E, int chunk, int nsb) {
    __shared__ int cur[128];
    int b = blockIdx.x;
    for (int i = threadIdx.x; i < nsb; i += 256) cur[i] = bho[i * NBP + b];
    __syncthreads();
    int beg = b * chunk, end = min(E, beg + chunk);
    for (int e = beg + threadIdx.x; e < end; e += 256) {
        int src = ei[e];
        int dst = ei[E + e];
        int a0 = ea[2 * e], a1 = ea[2 * e + 1];
        int pos = atomicAdd(&cur[dst >> SBSH], 1);
        rec[pos] = src | ((a0 * 3 + a1) << 17) | ((dst & (SBN - 1)) << 21);
    }
}

__global__ __launch_bounds__(1024) void csr_k(const int* __restrict__ rec,
                                              const int* __restrict__ bho,
                                              int* __restrict__ offs,
                                              int* __restrict__ packed,
                                              int nsb, int M, int E) {
    __shared__ int hist[SBN];
    __shared__ int lstart[SBN];
    __shared__ int wsum[16];
    int s = blockIdx.x;
    int t = threadIdx.x;
    int sb0 = bho[s * NBP];
    int sb1 = (s == nsb - 1) ? E : bho[(s + 1) * NBP];
    hist[t] = 0;
    __syncthreads();
    for (int i = sb0 + t; i < sb1; i += 1024)
        atomicAdd(&hist[(rec[i] >> 21) & (SBN - 1)], 1);
    __syncthreads();
    int v = hist[t];
    int lane = t & 63, wid = t >> 6;
    int ss = v;
    #pragma unroll
    for (int o = 1; o < 64; o <<= 1) { int u = __shfl_up(ss, o, 64); if (lane >= o) ss += u; }
    if (lane == 63) wsum[wid] = ss;
    __syncthreads();
    if (t == 0) { int c = 0; for (int w = 0; w < 16; ++w) { int x = wsum[w]; wsum[w] = c; c += x; } }
    __syncthreads();
    int excl = ss - v + wsum[wid];
    lstart[t] = excl;
    int node = (s << SBSH) + t;
    if (node < M) offs[node] = sb0 + excl;
    hist[t] = 0;
    __syncthreads();
    for (int i = sb0 + t; i < sb1; i += 1024) {
        int r = rec[i];
        int dl = (r >> 21) & (SBN - 1);
        int pos = sb0 + lstart[dl] + atomicAdd(&hist[dl], 1);
        packed[pos] = r & 0x1FFFFF;
    }
}

// per-dst gather-reduce: 1 wave per row, 4 rows/block, 8-deep unroll (r5 config)
__global__ __launch_bounds__(256) void agg_k(const unsigned short* __restrict__ h,
                                             const int* __restrict__ packed,
                                             const int* __restrict__ offs,
                                             const float* __restrict__ emb1,
                                             const float* __restrict__ emb2,
                                             unsigned int* __restrict__ aggb, int M) {
    __shared__ float emb12[10][DD];
    for (int t = threadIdx.x; t < 10 * DD; t += 256) {
        int c = t >> 7, col = t & 127;
        float v;
        if (c == 9) v = emb1[4 * DD + col] + emb2[col];          // self-loop emb
        else        v = emb1[(c / 3) * DD + col] + emb2[(c % 3) * DD + col];
        emb12[c][col] = v;
    }
    __syncthreads();
    int wid = threadIdx.x >> 6, lane = threadIdx.x & 63;
    int n = blockIdx.x * 4 + wid;
    if (n >= M) return;
    n = __builtin_amdgcn_readfirstlane(n);      // wave-uniform -> scalar addressing
    int c2 = lane * 2;
    int beg = offs[n], end = offs[n + 1];
    unsigned int hn = *(const unsigned int*)&h[(size_t)n * DD + c2];
    float2 se = *(const float2*)&emb12[9][c2];
    float2 acc = {bf2f_lo(hn) + se.x, bf2f_hi(hn) + se.y};
    int e = beg;
    for (; e + 8 <= end; e += 8) {
        int p[8]; unsigned int hv[8]; float2 m[8];
        #pragma unroll
        for (int i = 0; i < 8; ++i) p[i] = packed[e + i];
        #pragma unroll
        for (int i = 0; i < 8; ++i)
            hv[i] = *(const unsigned int*)&h[(size_t)(p[i] & 0x1FFFF) * DD + c2];
        #pragma unroll
        for (int i = 0; i < 8; ++i)
            m[i] = *(const float2*)&emb12[(p[i] >> 17) & 15][c2];
        #pragma unroll
        for (int i = 0; i < 8; ++i) {
            acc.x += bf2f_lo(hv[i]) + m[i].x;
            acc.y += bf2f_hi(hv[i]) + m[i].y;
        }
    }
    if (e + 4 <= end) {
        int p[4]; unsigned int hv[4]; float2 m[4];
        #pragma unroll
        for (int i = 0; i < 4; ++i) p[i] = packed[e + i];
        #pragma unroll
        for (int i = 0; i < 4; ++i)
            hv[i] = *(const unsigned int*)&h[(size_t)(p[i] & 0x1FFFF) * DD + c2];
        #pragma unroll
        for (int i = 0; i < 4; ++i)
            m[i] = *(const float2*)&emb12[(p[i] >> 17) & 15][c2];
        #pragma unroll
        for (int i = 0; i < 4; ++i) {
            acc.x += bf2f_lo(hv[i]) + m[i].x;
            acc.y += bf2f_hi(hv[i]) + m[i].y;
        }
        e += 4;
    }
    for (; e < end; ++e) {
        int p = packed[e];
        unsigned int hv = *(const unsigned int*)&h[(size_t)(p & 0x1FFFF) * DD + c2];
        float2 m = *(const float2*)&emb12[(p >> 17) & 15][c2];
        acc.x += bf2f_lo(hv) + m.x;
        acc.y += bf2f_hi(hv) + m.y;
    }
    aggb[((size_t)n * DD + c2) >> 1] = ((unsigned int)f2bf(acc.y) << 16) | f2bf(acc.x);
}

extern "C" void kernel_launch(void* const* d_in, const int* in_sizes, int n_in,
                              void* d_out, int out_size, void* d_ws, size_t ws_size,
                              hipStream_t stream) {
    const float* x     = (const float*)d_in[0];
    const int*   ei    = (const int*)d_in[1];
    const int*   ea    = (const int*)d_in[2];
    const float* pa    = (const float*)d_in[3];
    const float* Wenc  = (const float*)d_in[4];
    const float* emb1  = (const float*)d_in[5];
    const float* emb2  = (const float*)d_in[6];
    const float* W1    = (const float*)d_in[7];
    const float* b1    = (const float*)d_in[8];
    const float* W2    = (const float*)d_in[9];
    const float* b2    = (const float*)d_in[10];
    float* out = (float*)d_out;

    const int M = in_sizes[0] / DD;
    const int E = in_sizes[1] / 2;
    const int nsb = (M + SBN - 1) >> SBSH;
    const int chunk = (E + NBP - 1) / NBP;

    char* ws = (char*)d_ws;
    size_t o = 0;
    unsigned short* h_bf  = (unsigned short*)(ws + o); o += (size_t)M * DD * 2;
    unsigned int*   aggb  = (unsigned int*)(ws + o);   o += (size_t)M * DD * 2;
    // overlay: CSR scratch (dead after agg_k) aliased with hid (written by GEMM2)
    char* reg = ws + o;
    unsigned short* hid = (unsigned short*)reg;                 // M*256 bf16
    int* rec    = (int*)reg;
    int* packed = (int*)(reg + (size_t)E * 4);
    int* offs   = (int*)(reg + (size_t)E * 8);
    int* bh     = (int*)(reg + (size_t)E * 8 + (size_t)(M + 1) * 4);
    int* bho    = bh + 128 * NBP;

    const int gm = (M + 127) / 128;
    dim3 blk(256);

    sbhist_k<<<dim3(NBP), blk, 0, stream>>>(ei, bh, E, chunk, nsb);
    sbscan_k<<<dim3(1), blk, 0, stream>>>(bh, bho, nsb * NBP, offs, M, E);
    part_k<<<dim3(NBP), blk, 0, stream>>>(ei, ea, bho, rec, E, chunk, nsb);
    csr_k<<<dim3(nsb), dim3(1024), 0, stream>>>(rec, bho, offs, packed, nsb, M, E);

    // h_bf = bf16( PReLU(x) @ Wenc^T )
    gemm2_k<128, 128, 0, false><<<dim3(gm, 1), blk, 0, stream>>>(
        x, Wenc, nullptr, nullptr, h_bf, pa, M);

    agg_k<<<dim3((M + 3) / 4), blk, 0, stream>>>(h_bf, packed, offs, emb1, emb2, aggb, M);

    // hid = bf16(relu(aggb @ W1^T + b1))
    gemm2_k<128, 256, 1, true><<<dim3(gm, 2), blk, 0, stream>>>(
        aggb, W1, b1, nullptr, hid, nullptr, M);

    // out = hid @ W2^T + b2
    gemm2_k<256, 128, 2, true><<<dim3(gm, 1), blk, 0, stream>>>(
        hid, W2, b2, out, nullptr, nullptr, M);
}

// Round 8
// 227.518 us; speedup vs baseline: 1.5338x; 1.1405x over previous
//
#include <hip/hip_runtime.h>
#include <hip/hip_bf16.h>

#define DD 128

typedef short bf16x8 __attribute__((ext_vector_type(8)));
typedef float f32x4 __attribute__((ext_vector_type(4)));

__device__ __forceinline__ float bf2f_lo(unsigned int u) {
    union { unsigned int v; float f; } x; x.v = u << 16; return x.f;
}
__device__ __forceinline__ float bf2f_hi(unsigned int u) {
    union { unsigned int v; float f; } x; x.v = u & 0xFFFF0000u; return x.f;
}
__device__ __forceinline__ unsigned short f2bf(float f) {
    union { float f; unsigned int u; } x; x.f = f;
    unsigned int u = x.u;
    unsigned int r = (u + 0x7FFFu + ((u >> 16) & 1u)) >> 16;  // RNE
    return (unsigned short)r;
}

// ---- GEMM1: W staged in LDS once; A streamed global->frags ----
// Hb = bf16( PReLU(A) @ W^T ), K = NOUT = 128
__global__ __launch_bounds__(256) void gemm1_k(
    const float* __restrict__ Ap, const float* __restrict__ W,
    unsigned short* __restrict__ Hb,
    const float* __restrict__ prelu_a, int M)
{
    const int K = 128;
    __shared__ unsigned short Wl[128][K + 8];   // stride 272B -> 2-way banks (free)
    const int tid = threadIdx.x;
    const int wid = tid >> 6, lane = tid & 63;
    const float pa = prelu_a[0];

    #pragma unroll
    for (int idx = tid; idx < 128 * K / 4; idx += 256) {
        int n = idx / (K / 4), kq = idx % (K / 4);
        float4 v = *(const float4*)&W[(size_t)n * K + kq * 4];
        ushort4 w;
        w.x = f2bf(v.x); w.y = f2bf(v.y); w.z = f2bf(v.z); w.w = f2bf(v.w);
        *(ushort4*)&Wl[n][kq * 4] = w;
    }
    __syncthreads();

    const int r0 = blockIdx.x * 128 + wid * 32;
    const int rl = lane & 15, kb = (lane >> 4) * 8;

    bf16x8 af[2][4];
    #pragma unroll
    for (int rf = 0; rf < 2; ++rf) {
        int row = r0 + rf * 16 + rl; if (row > M - 1) row = M - 1;
        #pragma unroll
        for (int kf = 0; kf < 4; ++kf) {
            float4 v0 = *(const float4*)&Ap[(size_t)row * K + kf * 32 + kb];
            float4 v1 = *(const float4*)&Ap[(size_t)row * K + kf * 32 + kb + 4];
            v0.x = v0.x >= 0.f ? v0.x : pa * v0.x;
            v0.y = v0.y >= 0.f ? v0.y : pa * v0.y;
            v0.z = v0.z >= 0.f ? v0.z : pa * v0.z;
            v0.w = v0.w >= 0.f ? v0.w : pa * v0.w;
            v1.x = v1.x >= 0.f ? v1.x : pa * v1.x;
            v1.y = v1.y >= 0.f ? v1.y : pa * v1.y;
            v1.z = v1.z >= 0.f ? v1.z : pa * v1.z;
            v1.w = v1.w >= 0.f ? v1.w : pa * v1.w;
            bf16x8 t;
            t[0] = (short)f2bf(v0.x); t[1] = (short)f2bf(v0.y);
            t[2] = (short)f2bf(v0.z); t[3] = (short)f2bf(v0.w);
            t[4] = (short)f2bf(v1.x); t[5] = (short)f2bf(v1.y);
            t[6] = (short)f2bf(v1.z); t[7] = (short)f2bf(v1.w);
            af[rf][kf] = t;
        }
    }

    f32x4 acc[8][2];
    const f32x4 zz = {0.f, 0.f, 0.f, 0.f};
    #pragma unroll
    for (int nt = 0; nt < 8; ++nt) { acc[nt][0] = zz; acc[nt][1] = zz; }

    #pragma unroll
    for (int nt = 0; nt < 8; ++nt) {
        bf16x8 bf[4];
        #pragma unroll
        for (int kf = 0; kf < 4; ++kf)
            bf[kf] = *(const bf16x8*)&Wl[nt * 16 + rl][kf * 32 + kb];
        #pragma unroll
        for (int rf = 0; rf < 2; ++rf)
            #pragma unroll
            for (int kf = 0; kf < 4; ++kf)
                acc[nt][rf] = __builtin_amdgcn_mfma_f32_16x16x32_bf16(af[rf][kf], bf[kf], acc[nt][rf], 0, 0, 0);
    }

    const int rq = (lane >> 4) * 4;
    #pragma unroll
    for (int nt = 0; nt < 8; ++nt) {
        int c = nt * 16 + rl;
        #pragma unroll
        for (int rf = 0; rf < 2; ++rf) {
            int rb = r0 + rf * 16 + rq;
            #pragma unroll
            for (int t = 0; t < 4; ++t) {
                int r = rb + t;
                if (r < M) Hb[(size_t)r * 128 + c] = f2bf(acc[nt][rf][t]);
            }
        }
    }
}

// ---- fused MLP: out = relu(aggb @ W1^T + b1) @ W2^T + b2 ; hid lives in LDS ----
__global__ __launch_bounds__(512) void mlp_k(
    const unsigned short* __restrict__ A,   // aggb [M][128] bf16
    const float* __restrict__ W1,           // [256][128]
    const float* __restrict__ b1,           // [256]
    const float* __restrict__ W2,           // [128][256]
    const float* __restrict__ b2,           // [128]
    float* __restrict__ out, int M)
{
    __shared__ unsigned short W1l[256][136];     // 69632 B (row 272B: 2-way banks)
    __shared__ unsigned short hidl[128][264];    // 67584 B (row 528B: 2-way banks)
    unsigned short (*W2l)[264] = (unsigned short (*)[264])&W1l[0][0];  // 67584 <= 69632

    const int tid = threadIdx.x;
    const int wid = tid >> 6, lane = tid & 63;   // 8 waves, 16 rows each
    const int rl = lane & 15, kb = (lane >> 4) * 8;
    const int rq = (lane >> 4) * 4;
    const int r0 = blockIdx.x * 128;

    // stage W1 (256x128 f32 -> bf16)
    #pragma unroll
    for (int idx = tid; idx < 256 * 32; idx += 512) {
        int n = idx >> 5, kq = idx & 31;
        float4 v = *(const float4*)&W1[(size_t)n * 128 + kq * 4];
        ushort4 w;
        w.x = f2bf(v.x); w.y = f2bf(v.y); w.z = f2bf(v.z); w.w = f2bf(v.w);
        *(ushort4*)&W1l[n][kq * 4] = w;
    }
    // A-frags: 16 rows per wave, K=128
    bf16x8 af[4];
    {
        int row = r0 + wid * 16 + rl; if (row > M - 1) row = M - 1;
        #pragma unroll
        for (int kf = 0; kf < 4; ++kf)
            af[kf] = *(const bf16x8*)&A[(size_t)row * 128 + kf * 32 + kb];
    }
    __syncthreads();

    // phase 1: hid rows [wid*16, +16) x 256 cols
    f32x4 acc1[16];
    const f32x4 zz = {0.f, 0.f, 0.f, 0.f};
    #pragma unroll
    for (int nt = 0; nt < 16; ++nt) acc1[nt] = zz;
    #pragma unroll
    for (int nt = 0; nt < 16; ++nt) {
        bf16x8 bf[4];
        #pragma unroll
        for (int kf = 0; kf < 4; ++kf)
            bf[kf] = *(const bf16x8*)&W1l[nt * 16 + rl][kf * 32 + kb];
        #pragma unroll
        for (int kf = 0; kf < 4; ++kf)
            acc1[nt] = __builtin_amdgcn_mfma_f32_16x16x32_bf16(af[kf], bf[kf], acc1[nt], 0, 0, 0);
    }
    #pragma unroll
    for (int nt = 0; nt < 16; ++nt) {
        int c = nt * 16 + rl;
        float bi = b1[c];
        #pragma unroll
        for (int t = 0; t < 4; ++t)
            hidl[wid * 16 + rq + t][c] = f2bf(fmaxf(acc1[nt][t] + bi, 0.f));
    }
    __syncthreads();   // W1l reads + hidl writes complete

    // stage W2 (128x256 f32 -> bf16) over W1l's region
    #pragma unroll
    for (int idx = tid; idx < 128 * 64; idx += 512) {
        int n = idx >> 6, kq = idx & 63;
        float4 v = *(const float4*)&W2[(size_t)n * 256 + kq * 4];
        ushort4 w;
        w.x = f2bf(v.x); w.y = f2bf(v.y); w.z = f2bf(v.z); w.w = f2bf(v.w);
        *(ushort4*)&W2l[n][kq * 4] = w;
    }
    __syncthreads();

    // phase 2: out rows [wid*16, +16) x 128 cols, K=256 from LDS hid
    bf16x8 af2[8];
    #pragma unroll
    for (int kf = 0; kf < 8; ++kf)
        af2[kf] = *(const bf16x8*)&hidl[wid * 16 + rl][kf * 32 + kb];
    f32x4 acc2[8];
    #pragma unroll
    for (int nt = 0; nt < 8; ++nt) acc2[nt] = zz;
    #pragma unroll
    for (int nt = 0; nt < 8; ++nt) {
        bf16x8 bf[8];
        #pragma unroll
        for (int kf = 0; kf < 8; ++kf)
            bf[kf] = *(const bf16x8*)&W2l[nt * 16 + rl][kf * 32 + kb];
        #pragma unroll
        for (int kf = 0; kf < 8; ++kf)
            acc2[nt] = __builtin_amdgcn_mfma_f32_16x16x32_bf16(af2[kf], bf[kf], acc2[nt], 0, 0, 0);
    }
    #pragma unroll
    for (int nt = 0; nt < 8; ++nt) {
        int c = nt * 16 + rl;
        float bi = b2[c];
        #pragma unroll
        for (int t = 0; t < 4; ++t) {
            int r = r0 + wid * 16 + rq + t;
            if (r < M) out[(size_t)r * 128 + c] = acc2[nt][t] + bi;
        }
    }
}

// ---- cache-local CSR build ----
// record: src(17) | combo<<17 (4) | dstlocal<<21 (10)

#define SBSH 10          // superbucket = 1024 dst nodes
#define SBN  1024
#define NBP 128

__global__ __launch_bounds__(256) void sbhist_k(const int* __restrict__ ei,
                                                int* __restrict__ bh,
                                                int E, int chunk, int nsb) {
    __shared__ int h4[4][128];
    int wid = threadIdx.x >> 6;
    for (int i = threadIdx.x; i < 4 * 128; i += 256) ((int*)h4)[i] = 0;
    __syncthreads();
    int b = blockIdx.x;
    int beg = b * chunk, end = min(E, beg + chunk);
    for (int e = beg + threadIdx.x; e < end; e += 256)
        atomicAdd(&h4[wid][ei[E + e] >> SBSH], 1);
    __syncthreads();
    for (int i = threadIdx.x; i < nsb; i += 256)
        bh[i * NBP + b] = h4[0][i] + h4[1][i] + h4[2][i] + h4[3][i];
}

__global__ __launch_bounds__(1024) void sbscan_k(const int* __restrict__ bh,
                                                 int* __restrict__ bho,
                                                 int ntot, int* __restrict__ offs,
                                                 int M, int E) {
    __shared__ int ws[16];
    int tid = threadIdx.x;
    int ch = (ntot + 1023) / 1024;
    int beg = tid * ch, end = min(ntot, beg + ch);
    int s = 0;
    for (int i = beg; i < end; ++i) s += bh[i];
    int lane = tid & 63, wid = tid >> 6;
    int ss = s;
    #pragma unroll
    for (int o = 1; o < 64; o <<= 1) { int t = __shfl_up(ss, o, 64); if (lane >= o) ss += t; }
    if (lane == 63) ws[wid] = ss;
    __syncthreads();
    if (tid == 0) { int c = 0; for (int w = 0; w < 16; ++w) { int t = ws[w]; ws[w] = c; c += t; } }
    __syncthreads();
    int excl = ss - s + ws[wid];
    for (int i = beg; i < end; ++i) { int t = bh[i]; bho[i] = excl; excl += t; }
    if (tid == 0) offs[M] = E;
}

__global__ __launch_bounds__(256) void part_k(const int* __restrict__ ei,
                                              const int* __restrict__ ea,
                                              const int* __restrict__ bho,
                                              int* __restrict__ rec,
                                              int E, int chunk, int nsb) {
    __shared__ int cur[128];
    int b = blockIdx.x;
    for (int i = threadIdx.x; i < nsb; i += 256) cur[i] = bho[i * NBP + b];
    __syncthreads();
    int beg = b * chunk, end = min(E, beg + chunk);
    for (int e = beg + threadIdx.x; e < end; e += 256) {
        int src = ei[e];
        int dst = ei[E + e];
        int2 aa = *(const int2*)&ea[2 * e];
        int pos = atomicAdd(&cur[dst >> SBSH], 1);
        rec[pos] = src | ((aa.x * 3 + aa.y) << 17) | ((dst & (SBN - 1)) << 21);
    }
}

__global__ __launch_bounds__(1024) void csr_k(const int* __restrict__ rec,
                                              const int* __restrict__ bho,
                                              int* __restrict__ offs,
                                              int* __restrict__ packed,
                                              int nsb, int M, int E) {
    __shared__ int hist[SBN];
    __shared__ int lstart[SBN];
    __shared__ int wsum[16];
    int s = blockIdx.x;
    int t = threadIdx.x;
    int sb0 = bho[s * NBP];
    int sb1 = (s == nsb - 1) ? E : bho[(s + 1) * NBP];
    hist[t] = 0;
    __syncthreads();
    for (int i = sb0 + t; i < sb1; i += 1024)
        atomicAdd(&hist[(rec[i] >> 21) & (SBN - 1)], 1);
    __syncthreads();
    int v = hist[t];
    int lane = t & 63, wid = t >> 6;
    int ss = v;
    #pragma unroll
    for (int o = 1; o < 64; o <<= 1) { int u = __shfl_up(ss, o, 64); if (lane >= o) ss += u; }
    if (lane == 63) wsum[wid] = ss;
    __syncthreads();
    if (t == 0) { int c = 0; for (int w = 0; w < 16; ++w) { int x = wsum[w]; wsum[w] = c; c += x; } }
    __syncthreads();
    int excl = ss - v + wsum[wid];
    lstart[t] = excl;
    int node = (s << SBSH) + t;
    if (node < M) offs[node] = sb0 + excl;
    hist[t] = 0;
    __syncthreads();
    for (int i = sb0 + t; i < sb1; i += 1024) {
        int r = rec[i];
        int dl = (r >> 21) & (SBN - 1);
        int pos = sb0 + lstart[dl] + atomicAdd(&hist[dl], 1);
        packed[pos] = r & 0x1FFFFF;
    }
}

// per-dst gather-reduce: 1 wave per row, 4 rows/block, 8-deep unroll
__global__ __launch_bounds__(256) void agg_k(const unsigned short* __restrict__ h,
                                             const int* __restrict__ packed,
                                             const int* __restrict__ offs,
                                             const float* __restrict__ emb1,
                                             const float* __restrict__ emb2,
                                             unsigned int* __restrict__ aggb, int M) {
    __shared__ float emb12[10][DD];
    for (int t = threadIdx.x; t < 10 * DD; t += 256) {
        int c = t >> 7, col = t & 127;
        float v;
        if (c == 9) v = emb1[4 * DD + col] + emb2[col];          // self-loop emb
        else        v = emb1[(c / 3) * DD + col] + emb2[(c % 3) * DD + col];
        emb12[c][col] = v;
    }
    __syncthreads();
    int wid = threadIdx.x >> 6, lane = threadIdx.x & 63;
    int n = blockIdx.x * 4 + wid;
    if (n >= M) return;
    n = __builtin_amdgcn_readfirstlane(n);      // wave-uniform -> scalar addressing
    int c2 = lane * 2;
    int beg = offs[n], end = offs[n + 1];
    unsigned int hn = *(const unsigned int*)&h[(size_t)n * DD + c2];
    float2 se = *(const float2*)&emb12[9][c2];
    float2 acc = {bf2f_lo(hn) + se.x, bf2f_hi(hn) + se.y};
    int e = beg;
    for (; e + 8 <= end; e += 8) {
        int p[8]; unsigned int hv[8]; float2 m[8];
        #pragma unroll
        for (int i = 0; i < 8; ++i) p[i] = packed[e + i];
        #pragma unroll
        for (int i = 0; i < 8; ++i)
            hv[i] = *(const unsigned int*)&h[(size_t)(p[i] & 0x1FFFF) * DD + c2];
        #pragma unroll
        for (int i = 0; i < 8; ++i)
            m[i] = *(const float2*)&emb12[(p[i] >> 17) & 15][c2];
        #pragma unroll
        for (int i = 0; i < 8; ++i) {
            acc.x += bf2f_lo(hv[i]) + m[i].x;
            acc.y += bf2f_hi(hv[i]) + m[i].y;
        }
    }
    if (e + 4 <= end) {
        int p[4]; unsigned int hv[4]; float2 m[4];
        #pragma unroll
        for (int i = 0; i < 4; ++i) p[i] = packed[e + i];
        #pragma unroll
        for (int i = 0; i < 4; ++i)
            hv[i] = *(const unsigned int*)&h[(size_t)(p[i] & 0x1FFFF) * DD + c2];
        #pragma unroll
        for (int i = 0; i < 4; ++i)
            m[i] = *(const float2*)&emb12[(p[i] >> 17) & 15][c2];
        #pragma unroll
        for (int i = 0; i < 4; ++i) {
            acc.x += bf2f_lo(hv[i]) + m[i].x;
            acc.y += bf2f_hi(hv[i]) + m[i].y;
        }
        e += 4;
    }
    for (; e < end; ++e) {
        int p = packed[e];
        unsigned int hv = *(const unsigned int*)&h[(size_t)(p & 0x1FFFF) * DD + c2];
        float2 m = *(const float2*)&emb12[(p >> 17) & 15][c2];
        acc.x += bf2f_lo(hv) + m.x;
        acc.y += bf2f_hi(hv) + m.y;
    }
    aggb[((size_t)n * DD + c2) >> 1] = ((unsigned int)f2bf(acc.y) << 16) | f2bf(acc.x);
}

extern "C" void kernel_launch(void* const* d_in, const int* in_sizes, int n_in,
                              void* d_out, int out_size, void* d_ws, size_t ws_size,
                              hipStream_t stream) {
    const float* x     = (const float*)d_in[0];
    const int*   ei    = (const int*)d_in[1];
    const int*   ea    = (const int*)d_in[2];
    const float* pa    = (const float*)d_in[3];
    const float* Wenc  = (const float*)d_in[4];
    const float* emb1  = (const float*)d_in[5];
    const float* emb2  = (const float*)d_in[6];
    const float* W1    = (const float*)d_in[7];
    const float* b1    = (const float*)d_in[8];
    const float* W2    = (const float*)d_in[9];
    const float* b2    = (const float*)d_in[10];
    float* out = (float*)d_out;

    const int M = in_sizes[0] / DD;
    const int E = in_sizes[1] / 2;
    const int nsb = (M + SBN - 1) >> SBSH;
    const int chunk = (E + NBP - 1) / NBP;

    char* ws = (char*)d_ws;
    size_t o = 0;
    unsigned short* h_bf  = (unsigned short*)(ws + o); o += (size_t)M * DD * 2;
    unsigned int*   aggb  = (unsigned int*)(ws + o);   o += (size_t)M * DD * 2;
    int* rec    = (int*)(ws + o); o += (size_t)E * 4;
    int* packed = (int*)(ws + o); o += (size_t)E * 4;
    int* offs   = (int*)(ws + o); o += (size_t)(M + 1) * 4;
    int* bh     = (int*)(ws + o); o += 128 * NBP * 4;
    int* bho    = (int*)(ws + o); o += 128 * NBP * 4;

    dim3 blk(256);

    sbhist_k<<<dim3(NBP), blk, 0, stream>>>(ei, bh, E, chunk, nsb);
    sbscan_k<<<dim3(1), dim3(1024), 0, stream>>>(bh, bho, nsb * NBP, offs, M, E);
    part_k<<<dim3(NBP), blk, 0, stream>>>(ei, ea, bho, rec, E, chunk, nsb);
    csr_k<<<dim3(nsb), dim3(1024), 0, stream>>>(rec, bho, offs, packed, nsb, M, E);

    // h_bf = bf16( PReLU(x) @ Wenc^T )
    gemm1_k<<<dim3((M + 127) / 128), blk, 0, stream>>>(x, Wenc, h_bf, pa, M);

    agg_k<<<dim3((M + 3) / 4), blk, 0, stream>>>(h_bf, packed, offs, emb1, emb2, aggb, M);

    // out = relu(aggb @ W1^T + b1) @ W2^T + b2   (hid in LDS)
    mlp_k<<<dim3((M + 127) / 128), dim3(512), 0, stream>>>(
        (const unsigned short*)aggb, W1, b1, W2, b2, out, M);
}